// Round 11
// baseline (186.487 us; speedup 1.0000x reference)
//
#include <hip/hip_runtime.h>
#include <hip/hip_bf16.h>

// FConv2d, round 16 = round-15 structure + DIAGNOSTIC rep-loop (reps=5).
// r15 result falsified the occupancy theory (2 blocks/CU: fconv ~26us,
// unchanged) => cost is occupancy-independent (traffic/writeback suspect).
// r14 taught: rocprof replay runs WARM, so 3 reps (~40us) missed top-5.
// reps=5 => profiled dispatch ~65-77us > 44us fills => fconv tops the
// table and we finally read FETCH/WRITE/MfmaUtil/VALUBusy/BANK_CONFLICT.
// Body is idempotent (pure function of x,wgt); end-of-rep barrier
// protects LDS restage; reps is a runtime arg (no specialization).
// Structure otherwise IDENTICAL to r15 (verified, absmax 0.015625):
//  - one output row per block: grid (32,16) = 512 blocks = 2 blocks/CU
//  - stage 3 input rows; waves: col-half x d-quads {0,4,8},{2,6},{1,5},{3,7}
//  - weights in LDS (flip + 0.5 folded), af = 9 ds_read_b128
//  - compute_d<D>: all LDS offsets compile-time immediates.

typedef __attribute__((ext_vector_type(8))) short short8;
typedef __attribute__((ext_vector_type(4))) float floatx4;

#define NT 512
#define LCH 168                 // padded channel-slot dim (160 used)
#define SROWS 34                // cols per staged row (32..33 zero apron)
#define XSROW (SROWS * LCH)

template<int D, bool DUP>
__device__ __forceinline__ void compute_d(const char* basep, const short8 af[9],
                                          float* opbase) {
    floatx4 a0 = {0.f,0.f,0.f,0.f}, a1 = {0.f,0.f,0.f,0.f};
    floatx4 b0 = {0.f,0.f,0.f,0.f}, b1 = {0.f,0.f,0.f,0.f};
#pragma unroll
    for (int u = 0; u < 3; ++u)
#pragma unroll
        for (int v = 0; v < 3; ++v) {
            const int t = u * 3 + v;
            const short8 ba = *(const short8*)(basep +
                ((u * SROWS + v) * LCH + 8 * (8 + D)) * 2);
            if (t & 1) a1 = __builtin_amdgcn_mfma_f32_16x16x32_bf16(af[t], ba, a1, 0, 0, 0);
            else       a0 = __builtin_amdgcn_mfma_f32_16x16x32_bf16(af[t], ba, a0, 0, 0, 0);
            if (!DUP) {
                const short8 bb = *(const short8*)(basep +
                    ((u * SROWS + v) * LCH + 8 * (8 - D)) * 2);
                if (t & 1) b1 = __builtin_amdgcn_mfma_f32_16x16x32_bf16(af[t], bb, b1, 0, 0, 0);
                else       b0 = __builtin_amdgcn_mfma_f32_16x16x32_bf16(af[t], bb, b0, 0, 0, 0);
            }
        }
    floatx4 acc = a0 + a1;
    if (DUP) acc = acc + acc;          // xa==xb: 2*(0.5W*xa) = W*xa, bit-identical
    else     acc = acc + (b0 + b1);
    float* op = opbase + D * 16384;    // D*16*1024 floats
    op[0]    = acc.x;
    op[1024] = acc.y;
    op[2048] = acc.z;
    op[3072] = acc.w;
    if (D >= 1 && D <= 7) {            // mirror channel group 16-D
        float* op2 = opbase + (16 - D) * 16384;
        op2[0]    = acc.x;
        op2[1024] = acc.y;
        op2[2048] = acc.z;
        op2[3072] = acc.w;
    }
}

__global__ __launch_bounds__(NT, 4)
void fconv_mfma(const float* __restrict__ x,
                const float* __restrict__ wgt,
                float* __restrict__ out,
                int reps) {
    __shared__ __align__(16) short xs[3 * XSROW];   // 34,272 B
    __shared__ __align__(16) short wf[9 * 640];     // 11,520 B

    const int r    = blockIdx.x;   // 0..31 : output row
    const int b    = blockIdx.y;   // 0..15
    const int tid  = threadIdx.x;
    const int lane = tid & 63;
    const int wv   = tid >> 6;

    for (int rep = 0; rep < reps; ++rep) {

    // ---- weights -> LDS: wf[(8-k)*640 + n*40 + oct*8 + (7-j)] = 0.5*W[n][8oct+j][k]
    {
        const int n  = tid >> 5;        // 0..15
        const int c2 = tid & 31;
        const float* wb = wgt + (size_t)(n * 32 + c2) * 9;
        const int pos = n * 40 + (c2 & 24) + (7 - (c2 & 7));
#pragma unroll
        for (int k = 0; k < 9; ++k) {
            __hip_bfloat16 h = __float2bfloat16(0.5f * wb[k]);
            wf[(8 - k) * 640 + pos] = __builtin_bit_cast(short, h);
        }
    }

    // ---- stage raw x rows r..r+2: 1920 granule tasks (lrow, col, oL) ----
    const float* xb_base = x + ((size_t)b << 17);
#pragma unroll
    for (int it = 0; it < 4; ++it) {
        const int idx = it * NT + tid;            // 0..2047
        if (idx < 1920) {
            const int col  = idx & 31;
            const int rest = idx >> 5;            // 0..59
            const int oL   = rest / 3;            // 0..19
            const int lrow = rest - oL * 3;       // 0..2
            const int grow = r + lrow;
            short8 g;
            if (grow < 32) {
                float v[8];
#pragma unroll
                for (int j = 0; j < 8; ++j) {
                    const int m = (oL * 8 + j - 95) & 127;   // channel (L-95) mod 128
                    v[j] = xb_base[((m << 5) + grow) * 32 + col];
                }
                union { __hip_bfloat162 h2[4]; short8 s8; } u;
#pragma unroll
                for (int p = 0; p < 4; ++p)
                    u.h2[p] = __float22bfloat162_rn(make_float2(v[2 * p], v[2 * p + 1]));
                g = u.s8;
            } else {
                g = short8{0, 0, 0, 0, 0, 0, 0, 0};
            }
            *(short8*)&xs[(lrow * SROWS + col) * LCH + oL * 8] = g;
        }
    }
    // s-apron (col 32,33) zeros: 3 lrow * 2 col * 20 oL = 120 granules
    if (tid < 120) {
        const int oL   = tid % 20;
        const int rem  = tid / 20;       // 0..5
        const int lrow = rem >> 1;
        const int col  = 32 + (rem & 1);
        short8 z = {0, 0, 0, 0, 0, 0, 0, 0};
        *(short8*)&xs[(lrow * SROWS + col) * LCH + oL * 8] = z;
    }

    __syncthreads();

    // ---- A fragments: 9 ds_read_b128 ----
    const int n = lane & 15;      // filter row / D col lane
    const int q = lane >> 4;      // k-octet
    short8 af[9];
#pragma unroll
    for (int t = 0; t < 9; ++t)
        af[t] = *(const short8*)&wf[t * 640 + n * 40 + q * 8];

    // ---- compute: wave -> (col-half, d-quad) ----
    const int half = wv & 1;
    const int dq   = wv >> 1;     // 0..3
    const int s0   = half << 4;

    // lane base (non-negative): col part + 8*(3-q); window imm uses 8*(8 +/- D)
    const char* basep = (const char*)xs + ((s0 + n) * LCH + 8 * (3 - q)) * 2;
    float* opbase = out + ((size_t)((b * 256 + q * 4) * 32 + r) << 5) + s0 + n;

    if (dq == 0) {
        compute_d<0, true >(basep, af, opbase);   // 9 MFMA
        compute_d<4, false>(basep, af, opbase);   // 18
        compute_d<8, true >(basep, af, opbase);   // 9   -> 36
    } else if (dq == 1) {
        compute_d<2, false>(basep, af, opbase);
        compute_d<6, false>(basep, af, opbase);   // 36
    } else if (dq == 2) {
        compute_d<1, false>(basep, af, opbase);
        compute_d<5, false>(basep, af, opbase);   // 36
    } else {
        compute_d<3, false>(basep, af, opbase);
        compute_d<7, false>(basep, af, opbase);   // 36
    }

    __syncthreads();   // protect LDS restage of next rep
    }                  // rep loop
}

extern "C" void kernel_launch(void* const* d_in, const int* in_sizes, int n_in,
                              void* d_out, int out_size, void* d_ws, size_t ws_size,
                              hipStream_t stream) {
    const float* x   = (const float*)d_in[0];   // (16,128,32,32) fp32
    const float* wgt = (const float*)d_in[1];   // (16,32,3,3)   fp32
    float* out = (float*)d_out;                 // (16,256,32,32) fp32
    (void)in_sizes; (void)n_in; (void)out_size; (void)d_ws; (void)ws_size;

    fconv_mfma<<<dim3(32, 16), dim3(NT), 0, stream>>>(x, wgt, out, 5);
}

// Round 12
// 68.911 us; speedup vs baseline: 2.7062x; 2.7062x over previous
//
#include <hip/hip_runtime.h>
#include <hip/hip_bf16.h>

// FConv2d, round 17: traffic fix from r16 counters (47MB fetch + 44MB write
// per rep = 91MB vs 25MB ideal; pure traffic-bound at 3.7TB/s, MfmaUtil 3.6%).
// Root cause: blocks of all 16 batches scatter over all 8 XCDs -> per-XCD x
// footprint ~8.4MB > 4MB L2 -> x re-read amplification (3-row halo x ch-dup
// = 3.75x) goes to fabric AND thrashes out lines (evict dirty -> re-RFO ->
// re-write: write 44MB = 2.6x out size).
// Fix (a): 1-D grid, batch->XCD swizzle  b=(bid&7)+8*((bid>>3)&1), r=bid>>4
//   (hardware round-robins bid%8 across XCDs) -> per-XCD set = 2 batches
//   x (0.52MB x + 1.05MB out) = 3.1MB < 4MB L2. x halo re-reads become L2
//   hits; out lines stay resident.
// Fix (b): one wave owns full 128-B out lines: waves = 8 d-groups
//   {0,8},{4},{2},{6},{1},{5},{3},{7} (36 MFMA each), loop s0 in {0,16}
//   internally -> both 64-B halves of each line from the same wave.
// Math/staging/LDS layout IDENTICAL to verified r15 (absmax 0.015625).
// Identity: out[b,d*16+n,r,s] = sum 0.5W[n,c2,2-u,2-v]*(xa+xb)[r+u,s+v];
// d=0/8: xa==xb -> acc doubled; mirror d'=16-d same acc.

typedef __attribute__((ext_vector_type(8))) short short8;
typedef __attribute__((ext_vector_type(4))) float floatx4;

#define NT 512
#define LCH 168                 // padded channel-slot dim (160 used)
#define SROWS 34                // cols per staged row (32..33 zero apron)
#define XSROW (SROWS * LCH)

template<int D, bool DUP>
__device__ __forceinline__ void compute_d(const char* basep, const short8 af[9],
                                          float* opbase) {
    floatx4 a0 = {0.f,0.f,0.f,0.f}, a1 = {0.f,0.f,0.f,0.f};
    floatx4 b0 = {0.f,0.f,0.f,0.f}, b1 = {0.f,0.f,0.f,0.f};
#pragma unroll
    for (int u = 0; u < 3; ++u)
#pragma unroll
        for (int v = 0; v < 3; ++v) {
            const int t = u * 3 + v;
            const short8 ba = *(const short8*)(basep +
                ((u * SROWS + v) * LCH + 8 * (8 + D)) * 2);
            if (t & 1) a1 = __builtin_amdgcn_mfma_f32_16x16x32_bf16(af[t], ba, a1, 0, 0, 0);
            else       a0 = __builtin_amdgcn_mfma_f32_16x16x32_bf16(af[t], ba, a0, 0, 0, 0);
            if (!DUP) {
                const short8 bb = *(const short8*)(basep +
                    ((u * SROWS + v) * LCH + 8 * (8 - D)) * 2);
                if (t & 1) b1 = __builtin_amdgcn_mfma_f32_16x16x32_bf16(af[t], bb, b1, 0, 0, 0);
                else       b0 = __builtin_amdgcn_mfma_f32_16x16x32_bf16(af[t], bb, b0, 0, 0, 0);
            }
        }
    floatx4 acc = a0 + a1;
    if (DUP) acc = acc + acc;          // xa==xb: 2*(0.5W*xa) = W*xa, bit-identical
    else     acc = acc + (b0 + b1);
    float* op = opbase + D * 16384;    // D*16*1024 floats
    op[0]    = acc.x;
    op[1024] = acc.y;
    op[2048] = acc.z;
    op[3072] = acc.w;
    if (D >= 1 && D <= 7) {            // mirror channel group 16-D
        float* op2 = opbase + (16 - D) * 16384;
        op2[0]    = acc.x;
        op2[1024] = acc.y;
        op2[2048] = acc.z;
        op2[3072] = acc.w;
    }
}

__global__ __launch_bounds__(NT, 4)
void fconv_mfma(const float* __restrict__ x,
                const float* __restrict__ wgt,
                float* __restrict__ out) {
    __shared__ __align__(16) short xs[3 * XSROW];   // 34,272 B
    __shared__ __align__(16) short wf[9 * 640];     // 11,520 B

    const int bid = blockIdx.x;    // 0..511
    // batch->XCD swizzle: hardware round-robins bid%8 over XCDs
    const int b   = (bid & 7) + (((bid >> 3) & 1) << 3);   // 0..15
    const int r   = bid >> 4;                              // 0..31
    const int tid  = threadIdx.x;
    const int lane = tid & 63;
    const int wv   = tid >> 6;

    // ---- weights -> LDS: wf[(8-k)*640 + n*40 + oct*8 + (7-j)] = 0.5*W[n][8oct+j][k]
    {
        const int nn = tid >> 5;        // 0..15
        const int c2 = tid & 31;
        const float* wb = wgt + (size_t)(nn * 32 + c2) * 9;
        const int pos = nn * 40 + (c2 & 24) + (7 - (c2 & 7));
#pragma unroll
        for (int k = 0; k < 9; ++k) {
            __hip_bfloat16 h = __float2bfloat16(0.5f * wb[k]);
            wf[(8 - k) * 640 + pos] = __builtin_bit_cast(short, h);
        }
    }

    // ---- stage raw x rows r..r+2: 1920 granule tasks (lrow, col, oL) ----
    const float* xb_base = x + ((size_t)b << 17);
#pragma unroll
    for (int it = 0; it < 4; ++it) {
        const int idx = it * NT + tid;            // 0..2047
        if (idx < 1920) {
            const int col  = idx & 31;
            const int rest = idx >> 5;            // 0..59
            const int oL   = rest / 3;            // 0..19
            const int lrow = rest - oL * 3;       // 0..2
            const int grow = r + lrow;
            short8 g;
            if (grow < 32) {
                float v[8];
#pragma unroll
                for (int j = 0; j < 8; ++j) {
                    const int m = (oL * 8 + j - 95) & 127;   // channel (L-95) mod 128
                    v[j] = xb_base[((m << 5) + grow) * 32 + col];
                }
                union { __hip_bfloat162 h2[4]; short8 s8; } u;
#pragma unroll
                for (int p = 0; p < 4; ++p)
                    u.h2[p] = __float22bfloat162_rn(make_float2(v[2 * p], v[2 * p + 1]));
                g = u.s8;
            } else {
                g = short8{0, 0, 0, 0, 0, 0, 0, 0};
            }
            *(short8*)&xs[(lrow * SROWS + col) * LCH + oL * 8] = g;
        }
    }
    // s-apron (col 32,33) zeros: 3 lrow * 2 col * 20 oL = 120 granules
    if (tid < 120) {
        const int oL   = tid % 20;
        const int rem  = tid / 20;       // 0..5
        const int lrow = rem >> 1;
        const int col  = 32 + (rem & 1);
        short8 z = {0, 0, 0, 0, 0, 0, 0, 0};
        *(short8*)&xs[(lrow * SROWS + col) * LCH + oL * 8] = z;
    }

    __syncthreads();

    // ---- A fragments: 9 ds_read_b128 ----
    const int n = lane & 15;      // filter row / D col lane
    const int q = lane >> 4;      // k-octet
    short8 af[9];
#pragma unroll
    for (int t = 0; t < 9; ++t)
        af[t] = *(const short8*)&wf[t * 640 + n * 40 + q * 8];

    // ---- compute: wave = one d-group, BOTH col-halves (full-line stores) ----
#pragma unroll
    for (int i = 0; i < 2; ++i) {
        const int s0 = i << 4;
        const char* basep = (const char*)xs + ((s0 + n) * LCH + 8 * (3 - q)) * 2;
        float* opbase = out + ((size_t)((b * 256 + q * 4) * 32 + r) << 5) + s0 + n;
        switch (wv) {
        case 0: compute_d<0, true >(basep, af, opbase);
                compute_d<8, true >(basep, af, opbase); break;  // 18 MFMA
        case 1: compute_d<4, false>(basep, af, opbase); break;  // 18
        case 2: compute_d<2, false>(basep, af, opbase); break;
        case 3: compute_d<6, false>(basep, af, opbase); break;
        case 4: compute_d<1, false>(basep, af, opbase); break;
        case 5: compute_d<5, false>(basep, af, opbase); break;
        case 6: compute_d<3, false>(basep, af, opbase); break;
        default: compute_d<7, false>(basep, af, opbase); break;
        }
    }
}

extern "C" void kernel_launch(void* const* d_in, const int* in_sizes, int n_in,
                              void* d_out, int out_size, void* d_ws, size_t ws_size,
                              hipStream_t stream) {
    const float* x   = (const float*)d_in[0];   // (16,128,32,32) fp32
    const float* wgt = (const float*)d_in[1];   // (16,32,3,3)   fp32
    float* out = (float*)d_out;                 // (16,256,32,32) fp32
    (void)in_sizes; (void)n_in; (void)out_size; (void)d_ws; (void)ws_size;

    fconv_mfma<<<dim3(512), dim3(NT), 0, stream>>>(x, wgt, out);
}